// Round 1
// baseline (21746.187 us; speedup 1.0000x reference)
//
#include <hip/hip_runtime.h>
#include <hip/hip_bf16.h>
#include <hip/hip_cooperative_groups.h>

namespace cg = cooperative_groups;

#define BB 256   // batch
#define TT 512   // time
#define HH 256   // hidden
#define EE 128   // embed
#define KK 15    // tags

__device__ __forceinline__ float fsig(float x) { return 1.0f / (1.0f + __expf(-x)); }
__device__ __forceinline__ float ftanh(float x) {
    float e = __expf(2.0f * x);
    return 1.0f - 2.0f / (e + 1.0f);
}

// ---------------- prep: transpose ids/labels to [T][B] ----------------
__global__ void prep_transpose(const int* __restrict__ cids, const int* __restrict__ labels,
                               int* __restrict__ cidsT, int* __restrict__ labelsT) {
    int idx = blockIdx.x * 256 + threadIdx.x;  // 0..262143
    int which = idx >> 17;
    int r = idx & 131071;
    int b = r >> 9, t = r & 511;
    if (which == 0) cidsT[t * BB + b] = cids[b * TT + t];
    else            labelsT[t * BB + b] = labels[b * TT + t];
}

// ---------------- tables: table[d][v][j] = b_d[j] + embed[v] . Wih_d[j] ----------------
__global__ void build_tables(const float* __restrict__ embed,
                             const float* __restrict__ WihF, const float* __restrict__ bF,
                             const float* __restrict__ WihB, const float* __restrict__ bB,
                             float* __restrict__ tableF, float* __restrict__ tableB) {
    int idx = blockIdx.x * 256 + threadIdx.x;  // 0..262143
    int d = idx >> 17;
    int r = idx & 131071;
    int v = r >> 10, j = r & 1023;
    const float* Wih = d ? WihB : WihF;
    const float* bias = d ? bB : bF;
    float s = bias[j];
    const float* em = embed + v * EE;
    const float* wr = Wih + j * EE;
#pragma unroll 8
    for (int e = 0; e < EE; ++e) s += em[e] * wr[e];
    (d ? tableB : tableF)[v * 1024 + j] = s;
}

// ---------------- BiLSTM cooperative kernel ----------------
// grid = 256 blocks x 256 threads. dir = bid>>7, jb = bid&127 owns h-cols {2jb, 2jb+1}.
// thread = batch row. h exchanged via global double-buffer, layout [dir][phase][k][b] bf16.
// em (h @ fcW_half) for each block's 2 batch rows computed one step lagged.
__global__ void __launch_bounds__(256, 1)
bilstm(const float* __restrict__ tableF, const float* __restrict__ tableB,
       const float* __restrict__ WhhF, const float* __restrict__ WhhB,
       const float* __restrict__ fcW,
       const int* __restrict__ cidsT,
       __hip_bfloat16* __restrict__ hbuf,
       float* __restrict__ emF, float* __restrict__ emB) {
    const int bid = blockIdx.x;
    const int dir = bid >> 7;
    const int jb = bid & 127;
    const int j0 = jb * 2;
    const int tid = threadIdx.x;

    const float* table = dir ? tableB : tableF;
    const float* Whh = dir ? WhhB : WhhF;
    float* emOut = dir ? emB : emF;

    __shared__ float w_lds[256][8];    // [k][out]  out = gate*2 + col
    __shared__ float fc_lds[15][257];  // fcW half for this direction (padded stride)
    __shared__ float p_lds[2][15][4];

#pragma unroll
    for (int o = 0; o < 8; ++o) {
        int row = (o >> 1) * HH + j0 + (o & 1);
        w_lds[tid][o] = Whh[row * HH + tid];
    }
    for (int kk = 0; kk < KK; ++kk)
        fc_lds[kk][tid] = fcW[kk * (2 * HH) + dir * HH + tid];
    __syncthreads();

    __hip_bfloat16* hbase = hbuf + dir * (2 * HH * BB);
    float c0 = 0.f, c1 = 0.f;

    cg::grid_group grid = cg::this_grid();

    for (int s = 0; s < TT; ++s) {
        const int t = dir ? (TT - 1 - s) : s;
        const int cid = cidsT[t * BB + tid];
        const float* tb = table + cid * 1024;
        float acc[8];
#pragma unroll
        for (int o = 0; o < 8; ++o)
            acc[o] = tb[(o >> 1) * HH + j0 + (o & 1)];

        if (s > 0) {
            const __hip_bfloat16* hp = hbase + ((s + 1) & 1) * (HH * BB);
#pragma unroll 8
            for (int k = 0; k < HH; ++k) {
                float h = __bfloat162float(hp[k * BB + tid]);
                float4 wa = *(const float4*)&w_lds[k][0];
                float4 wb = *(const float4*)&w_lds[k][4];
                acc[0] += h * wa.x; acc[1] += h * wa.y;
                acc[2] += h * wa.z; acc[3] += h * wa.w;
                acc[4] += h * wb.x; acc[5] += h * wb.y;
                acc[6] += h * wb.z; acc[7] += h * wb.w;
            }
            // em for previous time index (uses hp = h at te), rows j0, j0+1
            const int te = dir ? (t + 1) : (t - 1);
            if (tid < 120) {
                const int r = tid & 1;
                const int kk = (tid >> 1) % 15;
                const int q = tid / 30;
                const int row = j0 + r;
                float p = 0.f;
                const __hip_bfloat16* hq = hp + q * 64 * BB + row;
#pragma unroll 8
                for (int k2 = 0; k2 < 64; ++k2)
                    p += __bfloat162float(hq[k2 * BB]) * fc_lds[kk][q * 64 + k2];
                p_lds[r][kk][q] = p;
            }
            __syncthreads();
            if (tid < 30) {
                const int r = tid & 1, kk = tid >> 1;
                float v = p_lds[r][kk][0] + p_lds[r][kk][1] + p_lds[r][kk][2] + p_lds[r][kk][3];
                emOut[(te * BB + (j0 + r)) * KK + kk] = v;
            }
        }

        float i0 = fsig(acc[0]), i1 = fsig(acc[1]);
        float f0 = fsig(acc[2]), f1 = fsig(acc[3]);
        float g0 = ftanh(acc[4]), g1 = ftanh(acc[5]);
        float o0 = fsig(acc[6]), o1 = fsig(acc[7]);
        c0 = f0 * c0 + i0 * g0;
        c1 = f1 * c1 + i1 * g1;
        float h0 = o0 * ftanh(c0);
        float h1 = o1 * ftanh(c1);
        __hip_bfloat16* hw = hbase + (s & 1) * (HH * BB);
        hw[(j0 + 0) * BB + tid] = __float2bfloat16(h0);
        hw[(j0 + 1) * BB + tid] = __float2bfloat16(h1);

        grid.sync();
    }

    // tail: em for the final produced h (phase (TT-1)&1 == 1); time index fwd=TT-1, bwd=0
    {
        const __hip_bfloat16* hp = hbase + 1 * (HH * BB);
        const int te = dir ? 0 : (TT - 1);
        if (tid < 120) {
            const int r = tid & 1;
            const int kk = (tid >> 1) % 15;
            const int q = tid / 30;
            const int row = j0 + r;
            float p = 0.f;
            const __hip_bfloat16* hq = hp + q * 64 * BB + row;
#pragma unroll 8
            for (int k2 = 0; k2 < 64; ++k2)
                p += __bfloat162float(hq[k2 * BB]) * fc_lds[kk][q * 64 + k2];
            p_lds[r][kk][q] = p;
        }
        __syncthreads();
        if (tid < 30) {
            const int r = tid & 1, kk = tid >> 1;
            float v = p_lds[r][kk][0] + p_lds[r][kk][1] + p_lds[r][kk][2] + p_lds[r][kk][3];
            emOut[(te * BB + (j0 + r)) * KK + kk] = v;
        }
    }
}

// ---------------- CRF partition (den): 16-lane group per batch row ----------------
__global__ void crf_den(const float* __restrict__ emF, const float* __restrict__ emB,
                        const float* __restrict__ fcb, const float* __restrict__ start_t,
                        const float* __restrict__ end_t, const float* __restrict__ trans,
                        float* __restrict__ den) {
    const int tid = threadIdx.x;
    const int j = tid & 15;
    const int grp = tid >> 4;
    const int b = blockIdx.x * 16 + grp;
    const bool valid = j < KK;

    __shared__ float expT[15][16];  // expT[i][j] = exp(trans[i][j]); col 15 = 0
    if (tid < 240) {
        int i = tid >> 4, jj = tid & 15;
        expT[i][jj] = (jj < KK) ? __expf(trans[i * KK + jj]) : 0.f;
    }
    __syncthreads();

    float fcbj = valid ? fcb[j] : 0.f;
    float alpha = -1e30f;
    if (valid) alpha = start_t[j] + emF[b * KK + j] + emB[b * KK + j] + fcbj;

    for (int t = 1; t < TT; ++t) {
        float m = alpha;
#pragma unroll
        for (int off = 8; off; off >>= 1)
            m = fmaxf(m, __shfl_xor(m, off, 16));
        float e = __expf(alpha - m);
        float S = 0.f;
#pragma unroll
        for (int i = 0; i < KK; ++i)
            S += __shfl(e, i, 16) * expT[i][j];
        float emv = 0.f;
        if (valid) emv = emF[(t * BB + b) * KK + j] + emB[(t * BB + b) * KK + j] + fcbj;
        float na = m + __logf(S) + emv;
        alpha = valid ? na : -1e30f;
    }
    float v = valid ? (alpha + end_t[j]) : -1e30f;
    float m = v;
#pragma unroll
    for (int off = 8; off; off >>= 1) m = fmaxf(m, __shfl_xor(m, off, 16));
    float e = __expf(v - m);
#pragma unroll
    for (int off = 8; off; off >>= 1) e += __shfl_xor(e, off, 16);
    if (j == 0) den[b] = m + __logf(e);
}

// ---------------- CRF numerator partials over t-chunks ----------------
__global__ void crf_num_part(const float* __restrict__ emF, const float* __restrict__ emB,
                             const float* __restrict__ fcb, const float* __restrict__ start_t,
                             const float* __restrict__ trans, const int* __restrict__ labelsT,
                             float* __restrict__ part) {
    const int b = threadIdx.x;
    const int q = blockIdx.x;
    const int t0 = q * 64;
    float p = 0.f;
    int lp = (t0 > 0) ? labelsT[(t0 - 1) * BB + b] : 0;
    for (int t = t0; t < t0 + 64; ++t) {
        int l = labelsT[t * BB + b];
        float em = emF[(t * BB + b) * KK + l] + emB[(t * BB + b) * KK + l] + fcb[l];
        if (t == 0) p += start_t[l] + em;
        else        p += trans[lp * KK + l] + em;
        lp = l;
    }
    part[q * BB + b] = p;
}

// ---------------- finalize: loss = -mean(num - den) ----------------
__global__ void finalize(const float* __restrict__ part, const float* __restrict__ den,
                         const float* __restrict__ end_t, const int* __restrict__ labelsT,
                         float* __restrict__ out) {
    const int b = threadIdx.x;
    float num = 0.f;
#pragma unroll
    for (int q = 0; q < 8; ++q) num += part[q * BB + b];
    num += end_t[labelsT[(TT - 1) * BB + b]];
    float v = num - den[b];
    __shared__ float red[256];
    red[b] = v;
    __syncthreads();
    for (int st = 128; st; st >>= 1) {
        if (b < st) red[b] += red[b + st];
        __syncthreads();
    }
    if (b == 0) out[0] = -(red[0] / (float)BB);
}

extern "C" void kernel_launch(void* const* d_in, const int* in_sizes, int n_in,
                              void* d_out, int out_size, void* d_ws, size_t ws_size,
                              hipStream_t stream) {
    const int* char_ids   = (const int*)d_in[0];
    const int* labels     = (const int*)d_in[1];
    // d_in[2] = mask (all ones by construction; unused)
    const float* embed    = (const float*)d_in[3];
    const float* WihF     = (const float*)d_in[4];
    const float* WhhF     = (const float*)d_in[5];
    const float* bF       = (const float*)d_in[6];
    const float* WihB     = (const float*)d_in[7];
    const float* WhhB     = (const float*)d_in[8];
    const float* bB       = (const float*)d_in[9];
    const float* fcW      = (const float*)d_in[10];
    const float* fcb      = (const float*)d_in[11];
    const float* start_t  = (const float*)d_in[12];
    const float* end_t    = (const float*)d_in[13];
    const float* trans    = (const float*)d_in[14];

    char* w = (char*)d_ws;
    float* tableF = (float*)w;          w += 128 * 1024 * 4;
    float* tableB = (float*)w;          w += 128 * 1024 * 4;
    int* cidsT    = (int*)w;            w += 512 * 256 * 4;
    int* labelsT  = (int*)w;            w += 512 * 256 * 4;
    __hip_bfloat16* hbuf = (__hip_bfloat16*)w; w += 2 * 2 * 256 * 256 * 2;
    float* emF    = (float*)w;          w += 512 * 256 * 15 * 4;
    float* emB    = (float*)w;          w += 512 * 256 * 15 * 4;
    float* den    = (float*)w;          w += 256 * 4;
    float* part   = (float*)w;          w += 8 * 256 * 4;

    prep_transpose<<<1024, 256, 0, stream>>>(char_ids, labels, cidsT, labelsT);
    build_tables<<<1024, 256, 0, stream>>>(embed, WihF, bF, WihB, bB, tableF, tableB);

    void* args[] = { (void*)&tableF, (void*)&tableB, (void*)&WhhF, (void*)&WhhB,
                     (void*)&fcW, (void*)&cidsT, (void*)&hbuf, (void*)&emF, (void*)&emB };
    hipLaunchCooperativeKernel((void*)bilstm, dim3(256), dim3(256), args, 0, stream);

    crf_den<<<16, 256, 0, stream>>>(emF, emB, fcb, start_t, end_t, trans, den);
    crf_num_part<<<8, 256, 0, stream>>>(emF, emB, fcb, start_t, trans, labelsT, part);
    finalize<<<1, 256, 0, stream>>>(part, den, end_t, labelsT, (float*)d_out);
}

// Round 2
// 16246.672 us; speedup vs baseline: 1.3385x; 1.3385x over previous
//
#include <hip/hip_runtime.h>
#include <hip/hip_bf16.h>
#include <hip/hip_cooperative_groups.h>

#define BB 256   // batch
#define TT 512   // time
#define HH 256   // hidden
#define EE 128   // embed
#define KK 15    // tags

#define NGRP 16  // batch groups per direction
#define GB   16  // batch rows per group
#define NB   8   // blocks per group (j-partition)
#define COLS 32  // h-cols per block

// hws layout: [parity][dir][g][k(256)][b(16)]
#define HWS(p,d,gg,k,b2) (((((((p)*2+(d))*NGRP+(gg))*HH)+(k))*GB)+(b2))

__device__ __forceinline__ float fsig(float x) { return 1.0f / (1.0f + __expf(-x)); }
__device__ __forceinline__ float ftanh(float x) {
    float e = __expf(2.0f * x);
    return 1.0f - 2.0f / (e + 1.0f);
}

// ---------------- prep: transpose ids/labels to [T][B] ----------------
__global__ void prep_transpose(const int* __restrict__ cids, const int* __restrict__ labels,
                               int* __restrict__ cidsT, int* __restrict__ labelsT) {
    int idx = blockIdx.x * 256 + threadIdx.x;
    int which = idx >> 17;
    int r = idx & 131071;
    int b = r >> 9, t = r & 511;
    if (which == 0) cidsT[t * BB + b] = cids[b * TT + t];
    else            labelsT[t * BB + b] = labels[b * TT + t];
}

// ---------------- tables: table[d][v][j] = b_d[j] + embed[v] . Wih_d[j] ----------------
__global__ void build_tables(const float* __restrict__ embed,
                             const float* __restrict__ WihF, const float* __restrict__ bF,
                             const float* __restrict__ WihB, const float* __restrict__ bB,
                             float* __restrict__ tableF, float* __restrict__ tableB) {
    int idx = blockIdx.x * 256 + threadIdx.x;
    int d = idx >> 17;
    int r = idx & 131071;
    int v = r >> 10, j = r & 1023;
    const float* Wih = d ? WihB : WihF;
    const float* bias = d ? bB : bF;
    float s = bias[j];
    const float* em = embed + v * EE;
    const float* wr = Wih + j * EE;
#pragma unroll 8
    for (int e = 0; e < EE; ++e) s += em[e] * wr[e];
    (d ? tableB : tableF)[v * 1024 + j] = s;
}

// ---------------- BiLSTM: 8-block groups, weight-stationary in LDS ----------------
// bid = jb*32 + gi, gi = dir*16 + g. Same-group blocks share bid%32 -> same bid%8 (XCD).
__global__ void __launch_bounds__(256, 1)
bilstm(const float* __restrict__ tableF, const float* __restrict__ tableB,
       const float* __restrict__ WhhF, const float* __restrict__ WhhB,
       const float* __restrict__ fcW,
       const int* __restrict__ cidsT,
       float* __restrict__ hws,
       float* __restrict__ emF, float* __restrict__ emB,
       unsigned* __restrict__ cnt) {
    const int bid = blockIdx.x;
    const int gi  = bid & 31;
    const int jb  = bid >> 5;          // 0..7 (block within group)
    const int dir = gi >> 4;
    const int g   = gi & 15;
    const int tid = threadIdx.x;

    const float* table = dir ? tableB : tableF;
    const float* Whh   = dir ? WhhB : WhhF;
    float* emOut       = dir ? emB : emF;

    __shared__ float w_lds[256][128];             // 128 KiB: [k][o], o = gate*32+cl
    __shared__ float h_lds[16][257];              // 16.1 KiB: [b][k]
    __shared__ __hip_bfloat16 fc_lds[15][260];    // 7.8 KiB (dir half of fcW)
    __shared__ float gate_lds[16][129];           // 8.1 KiB: [b][o]

    // fill weights: rep over o, coalesced global read
    for (int o = 0; o < 128; ++o) {
        int row = (o >> 5) * HH + jb * COLS + (o & 31);
        w_lds[tid][o] = Whh[row * HH + tid];
    }
    for (int kk = 0; kk < KK; ++kk)
        fc_lds[kk][tid] = __float2bfloat16(fcW[kk * (2 * HH) + dir * HH + tid]);
    __syncthreads();

    const int b  = tid & 15;   // batch row within group (gate compute)
    const int u  = tid >> 4;   // 0..15 -> outputs [8u, 8u+8)
    const int bglob = g * GB + b;
    float c0 = 0.f, c1 = 0.f;

    for (int s = 0; s <= TT; ++s) {
        // ---- load h_prev (written step s-1) into LDS ----
        if (s > 0) {
            const float* src = hws + HWS((s + 1) & 1, dir, g, 0, 0) + tid * 16;
            float4 a0 = *(const float4*)(src + 0);
            float4 a1 = *(const float4*)(src + 4);
            float4 a2 = *(const float4*)(src + 8);
            float4 a3 = *(const float4*)(src + 12);
            h_lds[ 0][tid] = a0.x; h_lds[ 1][tid] = a0.y; h_lds[ 2][tid] = a0.z; h_lds[ 3][tid] = a0.w;
            h_lds[ 4][tid] = a1.x; h_lds[ 5][tid] = a1.y; h_lds[ 6][tid] = a1.z; h_lds[ 7][tid] = a1.w;
            h_lds[ 8][tid] = a2.x; h_lds[ 9][tid] = a2.y; h_lds[10][tid] = a2.z; h_lds[11][tid] = a2.w;
            h_lds[12][tid] = a3.x; h_lds[13][tid] = a3.y; h_lds[14][tid] = a3.z; h_lds[15][tid] = a3.w;
        }
        __syncthreads();

        float acc[8];
        if (s < TT) {
            // ---- gates: table gather + Whh @ h_prev ----
            const int t = dir ? (TT - 1 - s) : s;
            const int cid = cidsT[t * BB + bglob];
            const float* tb = table + cid * 1024;
#pragma unroll
            for (int i = 0; i < 8; ++i) {
                int o = u * 8 + i;
                acc[i] = tb[(o >> 5) * HH + jb * COLS + (o & 31)];
            }
            if (s > 0) {
                const float* hrow = &h_lds[b][0];
#pragma unroll 4
                for (int k = 0; k < HH; k += 4) {
                    float4 hv = *(const float4*)(hrow + k);
#pragma unroll
                    for (int d = 0; d < 4; ++d) {
                        float hh = (d == 0) ? hv.x : (d == 1) ? hv.y : (d == 2) ? hv.z : hv.w;
                        float4 wa = *(const float4*)&w_lds[k + d][u * 8];
                        float4 wb = *(const float4*)&w_lds[k + d][u * 8 + 4];
                        acc[0] += hh * wa.x; acc[1] += hh * wa.y;
                        acc[2] += hh * wa.z; acc[3] += hh * wa.w;
                        acc[4] += hh * wb.x; acc[5] += hh * wb.y;
                        acc[6] += hh * wb.z; acc[7] += hh * wb.w;
                    }
                }
            }
        }

        // ---- em for h produced at step s-1 (lagged), 2 batch rows per block ----
        if (s > 0 && tid < 240) {
            const int r   = tid / 120;
            const int rem = tid % 120;
            const int kk  = rem >> 3;
            const int q   = rem & 7;
            const int rloc = jb * 2 + r;
            float p = 0.f;
#pragma unroll 8
            for (int d = 0; d < 32; ++d) {
                int k = d * 8 + q;
                p += h_lds[rloc][k] * __bfloat162float(fc_lds[kk][k]);
            }
            p += __shfl_xor(p, 1, 8);
            p += __shfl_xor(p, 2, 8);
            p += __shfl_xor(p, 4, 8);
            if (q == 0) {
                const int te = dir ? (TT - s) : (s - 1);
                emOut[(te * BB + (g * GB + rloc)) * KK + kk] = p;
            }
        }

        if (s < TT) {
            // ---- stage gates, apply nonlinearity, write h ----
            __syncthreads();
#pragma unroll
            for (int i = 0; i < 8; ++i) gate_lds[b][u * 8 + i] = acc[i];
            __syncthreads();

            const int bb = tid & 15;
            const int cp = tid >> 4;       // 0..15 -> cols {2cp, 2cp+1}
            const int cl0 = 2 * cp, cl1 = 2 * cp + 1;
            float iv0 = gate_lds[bb][ 0 + cl0], iv1 = gate_lds[bb][ 0 + cl1];
            float fv0 = gate_lds[bb][32 + cl0], fv1 = gate_lds[bb][32 + cl1];
            float gv0 = gate_lds[bb][64 + cl0], gv1 = gate_lds[bb][64 + cl1];
            float ov0 = gate_lds[bb][96 + cl0], ov1 = gate_lds[bb][96 + cl1];
            c0 = fsig(fv0) * c0 + fsig(iv0) * ftanh(gv0);
            c1 = fsig(fv1) * c1 + fsig(iv1) * ftanh(gv1);
            float h0 = fsig(ov0) * ftanh(c0);
            float h1 = fsig(ov1) * ftanh(c1);
            hws[HWS(s & 1, dir, g, jb * COLS + cl0, bb)] = h0;
            hws[HWS(s & 1, dir, g, jb * COLS + cl1, bb)] = h1;

            // ---- group barrier (8 blocks), per-step counter ----
            __syncthreads();                       // drains vmcnt: h stores retired
            if (tid == 0) {
                unsigned* c = &cnt[s * 32 + gi];
                __hip_atomic_fetch_add(c, 1u, __ATOMIC_RELEASE, __HIP_MEMORY_SCOPE_AGENT);
                while (__hip_atomic_load(c, __ATOMIC_RELAXED, __HIP_MEMORY_SCOPE_AGENT) < NB)
                    __builtin_amdgcn_s_sleep(2);
            }
            __syncthreads();
            __threadfence();                       // acquire: invalidate stale L1/L2
        }
    }
}

// ---------------- CRF partition (den): 16-lane group per batch row ----------------
__global__ void crf_den(const float* __restrict__ emF, const float* __restrict__ emB,
                        const float* __restrict__ fcb, const float* __restrict__ start_t,
                        const float* __restrict__ end_t, const float* __restrict__ trans,
                        float* __restrict__ den) {
    const int tid = threadIdx.x;
    const int j = tid & 15;
    const int grp = tid >> 4;
    const int b = blockIdx.x * 16 + grp;
    const bool valid = j < KK;

    __shared__ float expT[15][16];
    if (tid < 240) {
        int i = tid >> 4, jj = tid & 15;
        expT[i][jj] = (jj < KK) ? __expf(trans[i * KK + jj]) : 0.f;
    }
    __syncthreads();

    float fcbj = valid ? fcb[j] : 0.f;
    float alpha = -1e30f;
    if (valid) alpha = start_t[j] + emF[b * KK + j] + emB[b * KK + j] + fcbj;

    for (int t = 1; t < TT; ++t) {
        float m = alpha;
#pragma unroll
        for (int off = 8; off; off >>= 1)
            m = fmaxf(m, __shfl_xor(m, off, 16));
        float e = __expf(alpha - m);
        float S = 0.f;
#pragma unroll
        for (int i = 0; i < KK; ++i)
            S += __shfl(e, i, 16) * expT[i][j];
        float emv = 0.f;
        if (valid) emv = emF[(t * BB + b) * KK + j] + emB[(t * BB + b) * KK + j] + fcbj;
        float na = m + __logf(S) + emv;
        alpha = valid ? na : -1e30f;
    }
    float v = valid ? (alpha + end_t[j]) : -1e30f;
    float m = v;
#pragma unroll
    for (int off = 8; off; off >>= 1) m = fmaxf(m, __shfl_xor(m, off, 16));
    float e = __expf(v - m);
#pragma unroll
    for (int off = 8; off; off >>= 1) e += __shfl_xor(e, off, 16);
    if (j == 0) den[b] = m + __logf(e);
}

// ---------------- CRF numerator partials over t-chunks ----------------
__global__ void crf_num_part(const float* __restrict__ emF, const float* __restrict__ emB,
                             const float* __restrict__ fcb, const float* __restrict__ start_t,
                             const float* __restrict__ trans, const int* __restrict__ labelsT,
                             float* __restrict__ part) {
    const int b = threadIdx.x;
    const int q = blockIdx.x;
    const int t0 = q * 64;
    float p = 0.f;
    int lp = (t0 > 0) ? labelsT[(t0 - 1) * BB + b] : 0;
    for (int t = t0; t < t0 + 64; ++t) {
        int l = labelsT[t * BB + b];
        float em = emF[(t * BB + b) * KK + l] + emB[(t * BB + b) * KK + l] + fcb[l];
        if (t == 0) p += start_t[l] + em;
        else        p += trans[lp * KK + l] + em;
        lp = l;
    }
    part[q * BB + b] = p;
}

// ---------------- finalize ----------------
__global__ void finalize(const float* __restrict__ part, const float* __restrict__ den,
                         const float* __restrict__ end_t, const int* __restrict__ labelsT,
                         float* __restrict__ out) {
    const int b = threadIdx.x;
    float num = 0.f;
#pragma unroll
    for (int q = 0; q < 8; ++q) num += part[q * BB + b];
    num += end_t[labelsT[(TT - 1) * BB + b]];
    float v = num - den[b];
    __shared__ float red[256];
    red[b] = v;
    __syncthreads();
    for (int st = 128; st; st >>= 1) {
        if (b < st) red[b] += red[b + st];
        __syncthreads();
    }
    if (b == 0) out[0] = -(red[0] / (float)BB);
}

extern "C" void kernel_launch(void* const* d_in, const int* in_sizes, int n_in,
                              void* d_out, int out_size, void* d_ws, size_t ws_size,
                              hipStream_t stream) {
    const int* char_ids   = (const int*)d_in[0];
    const int* labels     = (const int*)d_in[1];
    const float* embed    = (const float*)d_in[3];
    const float* WihF     = (const float*)d_in[4];
    const float* WhhF     = (const float*)d_in[5];
    const float* bF       = (const float*)d_in[6];
    const float* WihB     = (const float*)d_in[7];
    const float* WhhB     = (const float*)d_in[8];
    const float* bB       = (const float*)d_in[9];
    const float* fcW      = (const float*)d_in[10];
    const float* fcb      = (const float*)d_in[11];
    const float* start_t  = (const float*)d_in[12];
    const float* end_t    = (const float*)d_in[13];
    const float* trans    = (const float*)d_in[14];

    char* w = (char*)d_ws;
    float* tableF = (float*)w;          w += 128 * 1024 * 4;
    float* tableB = (float*)w;          w += 128 * 1024 * 4;
    int* cidsT    = (int*)w;            w += 512 * 256 * 4;
    int* labelsT  = (int*)w;            w += 512 * 256 * 4;
    float* hws    = (float*)w;          w += 2 * 2 * NGRP * HH * GB * 4;   // 1 MiB
    float* emF    = (float*)w;          w += 512 * 256 * 15 * 4;
    float* emB    = (float*)w;          w += 512 * 256 * 15 * 4;
    float* den    = (float*)w;          w += 256 * 4;
    float* part   = (float*)w;          w += 8 * 256 * 4;
    unsigned* cnt = (unsigned*)w;       w += 512 * 32 * 4;                 // 64 KiB

    hipMemsetAsync(cnt, 0, 512 * 32 * 4, stream);
    prep_transpose<<<1024, 256, 0, stream>>>(char_ids, labels, cidsT, labelsT);
    build_tables<<<1024, 256, 0, stream>>>(embed, WihF, bF, WihB, bB, tableF, tableB);

    void* args[] = { (void*)&tableF, (void*)&tableB, (void*)&WhhF, (void*)&WhhB,
                     (void*)&fcW, (void*)&cidsT, (void*)&hws, (void*)&emF, (void*)&emB,
                     (void*)&cnt };
    hipLaunchCooperativeKernel((void*)bilstm, dim3(256), dim3(256), args, 0, stream);

    crf_den<<<16, 256, 0, stream>>>(emF, emB, fcb, start_t, end_t, trans, den);
    crf_num_part<<<8, 256, 0, stream>>>(emF, emB, fcb, start_t, trans, labelsT, part);
    finalize<<<1, 256, 0, stream>>>(part, den, end_t, labelsT, (float*)d_out);
}

// Round 3
// 1859.950 us; speedup vs baseline: 11.6918x; 8.7350x over previous
//
#include <hip/hip_runtime.h>
#include <hip/hip_bf16.h>

#define BB 256   // batch
#define TT 512   // time
#define HH 256   // hidden
#define EE 128   // embed
#define KK 15    // tags

#define NGRP 16  // batch groups per direction
#define GB   16  // batch rows per group
#define NB   4   // blocks per group (j-partition)
#define BCOLS 64 // h cols per block

typedef __attribute__((ext_vector_type(8))) short short8;
typedef __attribute__((ext_vector_type(4))) float floatx4;
typedef __attribute__((ext_vector_type(4))) unsigned int uint4v;
typedef __attribute__((ext_vector_type(2))) unsigned int uint2v;

__device__ __forceinline__ float fsig(float x) { return 1.0f / (1.0f + __expf(-x)); }
__device__ __forceinline__ float ftanh(float x) {
    float e = __expf(2.0f * x);
    return 1.0f - 2.0f / (e + 1.0f);
}
__device__ __forceinline__ unsigned short f2b(float f) {
    __hip_bfloat16 h = __float2bfloat16(f);
    return *reinterpret_cast<unsigned short*>(&h);
}

// ---------------- prep: transpose ids/labels to [T][B] ----------------
__global__ void prep_transpose(const int* __restrict__ cids, const int* __restrict__ labels,
                               int* __restrict__ cidsT, int* __restrict__ labelsT) {
    int idx = blockIdx.x * 256 + threadIdx.x;
    int which = idx >> 17;
    int r = idx & 131071;
    int b = r >> 9, t = r & 511;
    if (which == 0) cidsT[t * BB + b] = cids[b * TT + t];
    else            labelsT[t * BB + b] = labels[b * TT + t];
}

// ---------------- tables: table[d][v][j] = b_d[j] + embed[v] . Wih_d[j] ----------------
__global__ void build_tables(const float* __restrict__ embed,
                             const float* __restrict__ WihF, const float* __restrict__ bF,
                             const float* __restrict__ WihB, const float* __restrict__ bB,
                             float* __restrict__ tableF, float* __restrict__ tableB) {
    int idx = blockIdx.x * 256 + threadIdx.x;
    int d = idx >> 17;
    int r = idx & 131071;
    int v = r >> 10, j = r & 1023;
    const float* Wih = d ? WihB : WihF;
    const float* bias = d ? bB : bF;
    float s = bias[j];
    const float* em = embed + v * EE;
    const float* wr = Wih + j * EE;
#pragma unroll 8
    for (int e = 0; e < EE; ++e) s += em[e] * wr[e];
    (d ? tableB : tableF)[v * 1024 + j] = s;
}

// ---------------- BiLSTM: MFMA, register-stationary weights, sc1 h-exchange ----------------
// 128 blocks: bid = jb*32 + gi; gi = dir*16 + g; jb in 0..3 owns h-cols [jb*64, jb*64+64).
// Wave w handles cols jb*64 + w*16 + (lane&15), all 4 gates.
// hws layout: [p][dir][g][col(256)][b(16)] bf16 (bits in ushort).
__global__ void __launch_bounds__(256, 1)
bilstm(const float* __restrict__ tableF, const float* __restrict__ tableB,
       const float* __restrict__ WhhF, const float* __restrict__ WhhB,
       const float* __restrict__ fcW,
       const int* __restrict__ cidsT,
       unsigned short* __restrict__ hws,
       float* __restrict__ emF, float* __restrict__ emB,
       unsigned* __restrict__ cnt) {
    const int bid = blockIdx.x;
    const int gi  = bid & 31;
    const int jb  = bid >> 5;          // 0..3
    const int dir = gi >> 4;
    const int g   = gi & 15;
    const int tid = threadIdx.x;
    const int lane = tid & 63;
    const int wv  = tid >> 6;          // 0..3
    const int lo  = lane & 15;
    const int hi  = lane >> 4;         // 0..3

    const float* table = dir ? tableB : tableF;
    const float* Whh   = dir ? WhhB : WhhF;
    float* emOut       = dir ? emB : emF;

    __shared__ __align__(16) unsigned short h_lds[16][264];  // [b][k], pad: stride 528B

    const int colg = jb * BCOLS + wv * 16 + lo;   // this lane's h-col (0..255)
    const int bglob0 = g * GB;

    // ---- preload Whh B-fragments: wfrag[q][kb], B[k][col]=Whh[q*HH+colg][k] ----
    short8 wfrag[4][8];
#pragma unroll
    for (int q = 0; q < 4; ++q) {
        const float* wrow = Whh + (size_t)(q * HH + colg) * HH;
#pragma unroll
        for (int kb = 0; kb < 8; ++kb) {
            const float4* p4 = (const float4*)(wrow + kb * 32 + hi * 8);
            float4 w0 = p4[0], w1 = p4[1];
            short8 f;
            f[0] = (short)f2b(w0.x); f[1] = (short)f2b(w0.y);
            f[2] = (short)f2b(w0.z); f[3] = (short)f2b(w0.w);
            f[4] = (short)f2b(w1.x); f[5] = (short)f2b(w1.y);
            f[6] = (short)f2b(w1.z); f[7] = (short)f2b(w1.w);
            wfrag[q][kb] = f;
        }
    }
    // ---- em B-fragments (fcW, only block jb==0 wave 0 uses them): B[k][tag] ----
    short8 efrag[8];
    if (jb == 0 && wv == 0) {
#pragma unroll
        for (int kb = 0; kb < 8; ++kb) {
            short8 f;
            if (lo < KK) {
                const float4* p4 = (const float4*)(fcW + lo * (2 * HH) + dir * HH + kb * 32 + hi * 8);
                float4 w0 = p4[0], w1 = p4[1];
                f[0] = (short)f2b(w0.x); f[1] = (short)f2b(w0.y);
                f[2] = (short)f2b(w0.z); f[3] = (short)f2b(w0.w);
                f[4] = (short)f2b(w1.x); f[5] = (short)f2b(w1.y);
                f[6] = (short)f2b(w1.z); f[7] = (short)f2b(w1.w);
            } else {
                for (int j = 0; j < 8; ++j) f[j] = 0;
            }
            efrag[kb] = f;
        }
    }

    float cst[4] = {0.f, 0.f, 0.f, 0.f};
    const int GSTRIDE = HH * GB;                 // 4096 ushorts per (p,dir,g) slab

    for (int s = 0; s <= TT; ++s) {
        // ---- load h_prev (written at step s-1) -> h_lds, cache-bypassing ----
        if (s > 0) {
            const unsigned short* src = hws + (size_t)((((s + 1) & 1) * 2 + dir) * NGRP + g) * GSTRIDE + tid * 16;
            uint4v v0, v1;
            asm volatile("global_load_dwordx4 %0, %2, off sc0 sc1\n\t"
                         "global_load_dwordx4 %1, %3, off sc0 sc1\n\t"
                         "s_waitcnt vmcnt(0)"
                         : "=&v"(v0), "=&v"(v1)
                         : "v"(src), "v"(src + 8)
                         : "memory");
            union { uint4v v; unsigned short u[8]; } U0, U1;
            U0.v = v0; U1.v = v1;
#pragma unroll
            for (int b = 0; b < 8; ++b) h_lds[b][tid] = U0.u[b];
#pragma unroll
            for (int b = 0; b < 8; ++b) h_lds[8 + b][tid] = U1.u[b];
        }
        __syncthreads();

        floatx4 acc[4];
        if (s < TT) {
            // ---- init acc with table gather (bias + x@Wih already folded) ----
            const int t = dir ? (TT - 1 - s) : s;
            int cids[4];
#pragma unroll
            for (int r = 0; r < 4; ++r) cids[r] = cidsT[t * BB + bglob0 + hi * 4 + r];
#pragma unroll
            for (int q = 0; q < 4; ++q) {
#pragma unroll
                for (int r = 0; r < 4; ++r)
                    acc[q][r] = table[cids[r] * 1024 + q * HH + colg];
            }
            // ---- gates += h_prev @ Whh^T via MFMA ----
            if (s > 0) {
#pragma unroll
                for (int kb = 0; kb < 8; ++kb) {
                    short8 a = *(const short8*)&h_lds[lo][kb * 32 + hi * 8];
#pragma unroll
                    for (int q = 0; q < 4; ++q)
                        acc[q] = __builtin_amdgcn_mfma_f32_16x16x32_bf16(a, wfrag[q][kb], acc[q], 0, 0, 0);
                }
            }
        }

        // ---- em for h produced at step s-1 (lagged), one wave of block jb==0 ----
        if (s > 0 && jb == 0 && wv == 0) {
            floatx4 eacc = {0.f, 0.f, 0.f, 0.f};
#pragma unroll
            for (int kb = 0; kb < 8; ++kb) {
                short8 a = *(const short8*)&h_lds[lo][kb * 32 + hi * 8];
                eacc = __builtin_amdgcn_mfma_f32_16x16x32_bf16(a, efrag[kb], eacc, 0, 0, 0);
            }
            if (lo < KK) {
                const int te = dir ? (TT - s) : (s - 1);
#pragma unroll
                for (int r = 0; r < 4; ++r)
                    emOut[(te * BB + bglob0 + hi * 4 + r) * KK + lo] = eacc[r];
            }
        }

        if (s < TT) {
            // ---- c/h update in C-fragment layout; store h (cache-bypassing) ----
            unsigned short hbits[4];
#pragma unroll
            for (int r = 0; r < 4; ++r) {
                float iv = acc[0][r], fv = acc[1][r], gv = acc[2][r], ov = acc[3][r];
                float cn = fsig(fv) * cst[r] + fsig(iv) * ftanh(gv);
                cst[r] = cn;
                hbits[r] = f2b(fsig(ov) * ftanh(cn));
            }
            uint2v pv;
            pv[0] = (unsigned)hbits[0] | ((unsigned)hbits[1] << 16);
            pv[1] = (unsigned)hbits[2] | ((unsigned)hbits[3] << 16);
            unsigned short* dst = hws + (size_t)(((s & 1) * 2 + dir) * NGRP + g) * GSTRIDE + colg * 16 + hi * 4;
            asm volatile("global_store_dwordx2 %0, %1, off sc0 sc1"
                         :: "v"(dst), "v"(pv) : "memory");
            asm volatile("s_waitcnt vmcnt(0)" ::: "memory");
            __syncthreads();

            // ---- group barrier: 4 arrivals, relaxed agent atomics (no L2 flush) ----
            if (tid == 0) {
                unsigned* c = &cnt[(s * 32 + gi) * 16];
                __hip_atomic_fetch_add(c, 1u, __ATOMIC_RELAXED, __HIP_MEMORY_SCOPE_AGENT);
                while (__hip_atomic_load(c, __ATOMIC_RELAXED, __HIP_MEMORY_SCOPE_AGENT) < NB)
                    __builtin_amdgcn_s_sleep(1);
            }
            __syncthreads();
        }
    }
}

// ---------------- CRF partition (den): 16-lane group per batch row ----------------
__global__ void crf_den(const float* __restrict__ emF, const float* __restrict__ emB,
                        const float* __restrict__ fcb, const float* __restrict__ start_t,
                        const float* __restrict__ end_t, const float* __restrict__ trans,
                        float* __restrict__ den) {
    const int tid = threadIdx.x;
    const int j = tid & 15;
    const int grp = tid >> 4;
    const int b = blockIdx.x * 16 + grp;
    const bool valid = j < KK;

    __shared__ float expT[15][16];
    if (tid < 240) {
        int i = tid >> 4, jj = tid & 15;
        expT[i][jj] = (jj < KK) ? __expf(trans[i * KK + jj]) : 0.f;
    }
    __syncthreads();

    float fcbj = valid ? fcb[j] : 0.f;
    float alpha = -1e30f;
    if (valid) alpha = start_t[j] + emF[b * KK + j] + emB[b * KK + j] + fcbj;

    for (int t = 1; t < TT; ++t) {
        float m = alpha;
#pragma unroll
        for (int off = 8; off; off >>= 1)
            m = fmaxf(m, __shfl_xor(m, off, 16));
        float e = __expf(alpha - m);
        float S = 0.f;
#pragma unroll
        for (int i = 0; i < KK; ++i)
            S += __shfl(e, i, 16) * expT[i][j];
        float emv = 0.f;
        if (valid) emv = emF[(t * BB + b) * KK + j] + emB[(t * BB + b) * KK + j] + fcbj;
        float na = m + __logf(S) + emv;
        alpha = valid ? na : -1e30f;
    }
    float v = valid ? (alpha + end_t[j]) : -1e30f;
    float m = v;
#pragma unroll
    for (int off = 8; off; off >>= 1) m = fmaxf(m, __shfl_xor(m, off, 16));
    float e = __expf(v - m);
#pragma unroll
    for (int off = 8; off; off >>= 1) e += __shfl_xor(e, off, 16);
    if (j == 0) den[b] = m + __logf(e);
}

// ---------------- CRF numerator partials over t-chunks ----------------
__global__ void crf_num_part(const float* __restrict__ emF, const float* __restrict__ emB,
                             const float* __restrict__ fcb, const float* __restrict__ start_t,
                             const float* __restrict__ trans, const int* __restrict__ labelsT,
                             float* __restrict__ part) {
    const int b = threadIdx.x;
    const int q = blockIdx.x;
    const int t0 = q * 64;
    float p = 0.f;
    int lp = (t0 > 0) ? labelsT[(t0 - 1) * BB + b] : 0;
    for (int t = t0; t < t0 + 64; ++t) {
        int l = labelsT[t * BB + b];
        float em = emF[(t * BB + b) * KK + l] + emB[(t * BB + b) * KK + l] + fcb[l];
        if (t == 0) p += start_t[l] + em;
        else        p += trans[lp * KK + l] + em;
        lp = l;
    }
    part[q * BB + b] = p;
}

// ---------------- finalize ----------------
__global__ void finalize(const float* __restrict__ part, const float* __restrict__ den,
                         const float* __restrict__ end_t, const int* __restrict__ labelsT,
                         float* __restrict__ out) {
    const int b = threadIdx.x;
    float num = 0.f;
#pragma unroll
    for (int q = 0; q < 8; ++q) num += part[q * BB + b];
    num += end_t[labelsT[(TT - 1) * BB + b]];
    float v = num - den[b];
    __shared__ float red[256];
    red[b] = v;
    __syncthreads();
    for (int st = 128; st; st >>= 1) {
        if (b < st) red[b] += red[b + st];
        __syncthreads();
    }
    if (b == 0) out[0] = -(red[0] / (float)BB);
}

extern "C" void kernel_launch(void* const* d_in, const int* in_sizes, int n_in,
                              void* d_out, int out_size, void* d_ws, size_t ws_size,
                              hipStream_t stream) {
    const int* char_ids   = (const int*)d_in[0];
    const int* labels     = (const int*)d_in[1];
    const float* embed    = (const float*)d_in[3];
    const float* WihF     = (const float*)d_in[4];
    const float* WhhF     = (const float*)d_in[5];
    const float* bF       = (const float*)d_in[6];
    const float* WihB     = (const float*)d_in[7];
    const float* WhhB     = (const float*)d_in[8];
    const float* bB       = (const float*)d_in[9];
    const float* fcW      = (const float*)d_in[10];
    const float* fcb      = (const float*)d_in[11];
    const float* start_t  = (const float*)d_in[12];
    const float* end_t    = (const float*)d_in[13];
    const float* trans    = (const float*)d_in[14];

    char* w = (char*)d_ws;
    float* tableF = (float*)w;              w += 128 * 1024 * 4;
    float* tableB = (float*)w;              w += 128 * 1024 * 4;
    int* cidsT    = (int*)w;                w += 512 * 256 * 4;
    int* labelsT  = (int*)w;                w += 512 * 256 * 4;
    unsigned short* hws = (unsigned short*)w; w += 2 * 2 * NGRP * HH * GB * 2;  // 512 KiB
    float* emF    = (float*)w;              w += 512 * 256 * 15 * 4;
    float* emB    = (float*)w;              w += 512 * 256 * 15 * 4;
    float* den    = (float*)w;              w += 256 * 4;
    float* part   = (float*)w;              w += 8 * 256 * 4;
    unsigned* cnt = (unsigned*)w;           w += 512 * 32 * 16 * 4;             // 1 MiB, padded

    hipMemsetAsync(cnt, 0, 512 * 32 * 16 * 4, stream);
    prep_transpose<<<1024, 256, 0, stream>>>(char_ids, labels, cidsT, labelsT);
    build_tables<<<1024, 256, 0, stream>>>(embed, WihF, bF, WihB, bB, tableF, tableB);

    void* args[] = { (void*)&tableF, (void*)&tableB, (void*)&WhhF, (void*)&WhhB,
                     (void*)&fcW, (void*)&cidsT, (void*)&hws, (void*)&emF, (void*)&emB,
                     (void*)&cnt };
    hipLaunchCooperativeKernel((void*)bilstm, dim3(128), dim3(256), args, 0, stream);

    crf_den<<<16, 256, 0, stream>>>(emF, emB, fcb, start_t, end_t, trans, den);
    crf_num_part<<<8, 256, 0, stream>>>(emF, emB, fcb, start_t, trans, labelsT, part);
    finalize<<<1, 256, 0, stream>>>(part, den, end_t, labelsT, (float*)d_out);
}